// Round 16
// baseline (389.595 us; speedup 1.0000x reference)
//
#include <hip/hip_runtime.h>
#include <math.h>

// Problem constants (reference: VOCAB=10000, HID=256, B=64, T=64)
#define VOCABN 10000
#define HIDN   256
#define GATES  1024   // 4*HID
#define BN     64
#define TN     64
#define BT     4096   // B*T
#define NCT    625    // vocab col-tiles of 16 (10000 = 625*16 exactly)

typedef unsigned int       u32;
typedef unsigned short     u16;
typedef unsigned long long u64;
typedef float v4f __attribute__((ext_vector_type(4)));
typedef short v8s __attribute__((ext_vector_type(8)));

__device__ __forceinline__ float bf2f(u16 u) {
    return __uint_as_float(((u32)u) << 16);
}
__device__ __forceinline__ u16 f2bf(float f) {          // round-to-nearest-even
    u32 u = __float_as_uint(f);
    u += 0x7FFFu + ((u >> 16) & 1u);
    return (u16)(u >> 16);
}
__device__ __forceinline__ float fast_sigmoid(float x) {
    return 1.0f / (1.0f + __expf(-x));
}
__device__ __forceinline__ float fast_tanh(float x) {
    float e = __expf(-2.0f * fabsf(x));
    float t = (1.0f - e) / (1.0f + e);
    return copysignf(t, x);
}
__device__ __forceinline__ u64 llc_load(const u64* p) {
    return __hip_atomic_load(p, __ATOMIC_RELAXED, __HIP_MEMORY_SCOPE_AGENT);
}
__device__ __forceinline__ void llc_store(u64* p, u64 v) {
    __hip_atomic_store(p, v, __ATOMIC_RELAXED, __HIP_MEMORY_SCOPE_AGENT);
}
__device__ __forceinline__ float llc_loadf(const float* p) {
    return __hip_atomic_load(p, __ATOMIC_RELAXED, __HIP_MEMORY_SCOPE_AGENT);
}
__device__ __forceinline__ void llc_storef(float* p, float v) {
    __hip_atomic_store(p, v, __ATOMIC_RELAXED, __HIP_MEMORY_SCOPE_AGENT);
}
__device__ __forceinline__ u32 cnt_add(u32* p) {
    return __hip_atomic_fetch_add(p, 1u, __ATOMIC_RELAXED,
                                  __HIP_MEMORY_SCOPE_AGENT);
}
__device__ __forceinline__ u32 cnt_read(u32* p) {
    return __hip_atomic_load(p, __ATOMIC_RELAXED, __HIP_MEMORY_SCOPE_AGENT);
}

// ---------------------------------------------------------------------------
// fp32 [HIDN][ncols] tile c -> bf16 MFMA B-fragment layout [c][8 q][64 l][8].
// Fragment (c,q), lane l holds B[k = q*32 + (l>>4)*8 + j][n = c*16 + (l&15)].
// Plain uint4 stores (writer-L2 cached; cross-kernel visibility via the
// end-of-dispatch flush — consumers are always later launches).
// ---------------------------------------------------------------------------
__device__ __forceinline__ void wfrag_dev(
    const float* __restrict__ src, u16* __restrict__ dst, int ncols, int c,
    int t, u16 lt[HIDN][16])
{
    const float* s = src + (size_t)t * ncols + c * 16;
    #pragma unroll
    for (int j4 = 0; j4 < 4; ++j4) {
        float4 v = *(const float4*)(s + j4 * 4);
        lt[t][j4*4+0] = f2bf(v.x);
        lt[t][j4*4+1] = f2bf(v.y);
        lt[t][j4*4+2] = f2bf(v.z);
        lt[t][j4*4+3] = f2bf(v.w);
    }
    __syncthreads();
    #pragma unroll
    for (int h = 0; h < 2; ++h) {
        int f = t + h * 256;             // frag id = q*64 + l
        int q = f >> 6, l = f & 63;
        int m = l & 15, kb = q * 32 + ((l >> 4) & 3) * 8;
        u32 w[4];
        #pragma unroll
        for (int j = 0; j < 4; ++j)
            w[j] = (u32)lt[kb + 2*j][m] | ((u32)lt[kb + 2*j + 1][m] << 16);
        *(uint4*)(dst + (((size_t)c * 8 + q) * 64 + l) * 8) =
            make_uint4(w[0], w[1], w[2], w[3]);
    }
}

// ---------------------------------------------------------------------------
// wfrag for both W_lstm halves (128 blocks) — fallback-path prep. Block 0
// also zeroes the plstm barrier + dense arrival counters.
// ---------------------------------------------------------------------------
__global__ __launch_bounds__(256) void k_wfrag2(
    const float* __restrict__ W_lstm,
    u16* __restrict__ Wxf, u16* __restrict__ Whf,
    u32* __restrict__ bar)           // [320] u32: plstm counters + sdone
{
    __shared__ u16 lt[HIDN][16];
    const int bid = blockIdx.x;
    if (bid == 0) {
        bar[threadIdx.x] = 0u;
        if (threadIdx.x < 64) bar[256 + threadIdx.x] = 0u;
    }
    if (bid < 64)
        wfrag_dev(W_lstm, Wxf, GATES, bid, threadIdx.x, lt);
    else
        wfrag_dev(W_lstm + (size_t)HIDN * GATES, Whf, GATES, bid - 64,
                  threadIdx.x, lt);
}

// ---------------------------------------------------------------------------
// ALL THREE weight transforms in one launch (753 blocks) — wide-ws path.
//   0..63: W_lstm x-part -> Wxf | 64..127: h-part -> Whf | 128..752: W_dense
// Block 0 zeroes the plstm barrier + dense arrival counters.
// ---------------------------------------------------------------------------
__global__ __launch_bounds__(256) void k_wfrag3(
    const float* __restrict__ W_lstm,
    const float* __restrict__ W_dense,
    u16* __restrict__ Wxf, u16* __restrict__ Whf, u16* __restrict__ Wf,
    u32* __restrict__ bar)
{
    __shared__ u16 lt[HIDN][16];
    const int bid = blockIdx.x;
    if (bid == 0) {
        bar[threadIdx.x] = 0u;
        if (threadIdx.x < 64) bar[256 + threadIdx.x] = 0u;
    }
    if (bid < 64)
        wfrag_dev(W_lstm, Wxf, GATES, bid, threadIdx.x, lt);
    else if (bid < 128)
        wfrag_dev(W_lstm + (size_t)HIDN * GATES, Whf, GATES, bid - 64,
                  threadIdx.x, lt);
    else
        wfrag_dev(W_dense, Wf, VOCABN, bid - 128, threadIdx.x, lt);
}

// ---------------------------------------------------------------------------
// wfrag for W_dense (625 blocks) — fallback path, runs AFTER plstm (Wf
// aliases gx there).
// ---------------------------------------------------------------------------
__global__ __launch_bounds__(256) void k_wfrag(
    const float* __restrict__ src,   // [HIDN][ncols]
    u16*         __restrict__ dst,   // [nct][8][64][8]
    int ncols)
{
    __shared__ u16 lt[HIDN][16];
    wfrag_dev(src, dst, ncols, blockIdx.x, threadIdx.x, lt);
}

// ---------------------------------------------------------------------------
// Kernel 1 (MFMA): gates_x = E[idx] @ W_x + b_lstm. 256 blocks x 16 rows.
// gx stays fp32: bf16 gx cost plstm +14us (R9 vs R10 A/B).
// ---------------------------------------------------------------------------
__global__ __launch_bounds__(256) void k_xgates(
    const int*   __restrict__ idx,   // [BT]
    const float* __restrict__ E,     // [VOCAB][HIDN]
    const u16*   __restrict__ Wxf,   // [64][8][64][8]
    const float* __restrict__ bl,    // [GATES]
    float*       __restrict__ gx)    // [BT][GATES]
{
    const int r0   = blockIdx.x * 16;
    const int tid  = threadIdx.x;
    const int w    = tid >> 6, lane = tid & 63;
    const int m    = lane & 15, quad = lane >> 4;

    v8s a[8];
    {
        const float* e = E + (size_t)idx[r0 + m] * HIDN + quad * 8;
        #pragma unroll
        for (int q = 0; q < 8; ++q) {
            float4 x0 = *(const float4*)(e + q * 32);
            float4 x1 = *(const float4*)(e + q * 32 + 4);
            uint4 t4 = make_uint4(
                (u32)f2bf(x0.x) | ((u32)f2bf(x0.y) << 16),
                (u32)f2bf(x0.z) | ((u32)f2bf(x0.w) << 16),
                (u32)f2bf(x1.x) | ((u32)f2bf(x1.y) << 16),
                (u32)f2bf(x1.z) | ((u32)f2bf(x1.w) << 16));
            a[q] = *(v8s*)&t4;
        }
    }

    for (int c = w; c < GATES / 16; c += 4) {
        v4f acc = {0.f, 0.f, 0.f, 0.f};
        #pragma unroll
        for (int q = 0; q < 8; ++q) {
            v8s b = *(const v8s*)(Wxf + (((size_t)c * 8 + q) * 64 + lane) * 8);
            acc = __builtin_amdgcn_mfma_f32_16x16x32_bf16(a[q], b, acc, 0, 0, 0);
        }
        const int col = c * 16 + m;
        const float bv = bl[col];
        #pragma unroll
        for (int r = 0; r < 4; ++r)   // D: col=lane&15, row=quad*4+r (m89/m91)
            gx[(size_t)(r0 + quad * 4 + r) * GATES + col] = acc[r] + bv;
    }
}

// ---------------------------------------------------------------------------
// Kernel 2 (persistent MFMA LSTM — R10/R14's proven 209us config VERBATIM):
// 64 blocks = 4 row-groups(16 rows) x 16 unit-slices. W_h slice LDS-resident.
// Cross-block h-exchange through the LLC ONLY via relaxed agent u64 ops.
// Counter barrier per step (flag-array variant was +11us, R12 A/B).
// Runs ALONE (R7/R8: co-running dense cost this kernel 1.7x).
// ---------------------------------------------------------------------------
__global__ __launch_bounds__(256) void k_plstm(
    const u16*   __restrict__ Whf,   // [64 ct][8][64][8] h-part frags
    const float* __restrict__ gx,    // [BT][GATES]
    u16*                      Hx,    // [2][BN][HIDN] bf16 exchange (LLC)
    u16*         __restrict__ Hb,    // [BT][HIDN] bf16 output
    u32*                      bar)   // counters (stride 64), zeroed by prep
{
    __shared__ uint4 Wl4[4 * 512];       // 32 KB: [ct][8 q][64 l][8] u16
    __shared__ float gl[4][16][16];      // 4 KB gate exchange

    const int tid  = threadIdx.x;
    const int rg   = blockIdx.x >> 4;    // row group: batch rows rg*16..+15
    const int ns   = blockIdx.x & 15;    // unit slice: units ns*16..+15
    const int u0   = ns * 16;
    const int w    = tid >> 6;           // wave = gate type (i,j,f,o)
    const int lane = tid & 63;
    const int m    = lane & 15, kq = lane >> 4;

    {   // load W_h slice: tiles c = w'*16 + ns, 8 KB contiguous each
        const uint4* src = (const uint4*)Whf;
        #pragma unroll
        for (int i = 0; i < 8; ++i) {
            int e  = tid + i * 256;          // [0, 2048)
            int ct = e >> 9, off = e & 511;  // 512 uint4 per tile
            Wl4[e] = src[(size_t)(ct * 16 + ns) * 512 + off];
        }
    }
    {   // zero gate-exchange so t=0 reads 0 for the h@W_h term
        float* g0 = (float*)gl;
        #pragma unroll
        for (int j = 0; j < 4; ++j) g0[tid * 4 + j] = 0.0f;
    }
    __syncthreads();

    const u16* Wl = (const u16*)Wl4;

    const int r = tid >> 4, u = tid & 15;
    const int b = rg * 16 + r;                       // batch row
    const float* gxp = gx + (size_t)b * TN * GATES + u0 + u;
    u16* hbp = Hb + (size_t)b * TN * HIDN + u0 + u;
    const int hxw = b * HIDN + u0 + u;               // Hx elem offset (in-buf)
    const int aoff = (rg * 16 + m) * HIDN + kq * 8;  // a-frag elem offset

    float cstate = 0.0f;
    float4 gxr;
    gxr.x = gxp[0]; gxr.y = gxp[256]; gxr.z = gxp[512]; gxr.w = gxp[768];

    for (int t = 0; t < TN; ++t) {
        // prefetch next step's x-gates early (hide HBM latency behind MFMA)
        float4 gxn = gxr;
        if (t + 1 < TN) {
            const float* p = gxp + (size_t)(t + 1) * GATES;
            gxn.x = p[0]; gxn.y = p[256]; gxn.z = p[512]; gxn.w = p[768];
        }

        if (t > 0) {
            // a-frags from LLC: relaxed agent u64 atomic loads (sc0 sc1)
            const u64* hsrc = (const u64*)(Hx + (t & 1) * (BN * HIDN) + aoff);
            v4f acc = {0.f, 0.f, 0.f, 0.f};
            #pragma unroll
            for (int q = 0; q < 8; ++q) {
                union { u64 d[2]; v8s v; } av;
                av.d[0] = llc_load(hsrc + q * 8);
                av.d[1] = llc_load(hsrc + q * 8 + 1);
                v8s bf = *(const v8s*)(Wl + ((w * 8 + q) * 64 + lane) * 8);
                acc = __builtin_amdgcn_mfma_f32_16x16x32_bf16(av.v, bf, acc, 0, 0, 0);
            }
            #pragma unroll
            for (int rr = 0; rr < 4; ++rr)   // row = kq*4+rr, col(unit) = m
                gl[w][kq * 4 + rr][m] = acc[rr];
        }
        __syncthreads();

        {   // cell update for (r, u); c stays in a register
            float ai = gl[0][r][u] + gxr.x;
            float aj = gl[1][r][u] + gxr.y;
            float af = gl[2][r][u] + gxr.z;
            float ao = gl[3][r][u] + gxr.w;
            float ig = fast_sigmoid(ai);
            float fg = fast_sigmoid(af + 1.0f);      // forget_bias = 1.0
            float og = fast_sigmoid(ao);
            float jt = fast_tanh(aj);
            cstate = fg * cstate + ig * jt;
            float hn = og * fast_tanh(cstate);
            u32 hv = f2bf(hn);
            hbp[(size_t)t * HIDN] = (u16)hv;

            if (t + 1 < TN) {
                // pack 4 consecutive units (same row, lanes tid..tid+3) into
                // one u64 and publish via relaxed agent atomic store -> LLC
                u32 p1 = __shfl_down(hv, 1);
                u32 p2 = __shfl_down(hv, 2);
                u32 p3 = __shfl_down(hv, 3);
                if ((tid & 3) == 0) {
                    u64 pk = (u64)(hv | (p1 << 16))
                           | ((u64)(p2 | (p3 << 16)) << 32);
                    u64* dst = (u64*)(Hx + (((t & 1) ^ 1) * (BN * HIDN)) + hxw);
                    llc_store(dst, pk);
                }
            }
        }

        if (t + 1 < TN) {
            __syncthreads();   // per-wave vmcnt(0) before s_barrier: all
                               // publish stores have reached the LLC
            if (tid == 0) {
                cnt_add(&bar[rg * 64]);
                u32 tgt = (u32)(t + 1) * 16u;
                while (cnt_read(&bar[rg * 64]) < tgt)
                    __builtin_amdgcn_s_sleep(1);
            }
            __syncthreads();   // broadcast release; also orders next gl writes
        }
        gxr = gxn;
    }
}

// ---------------------------------------------------------------------------
// Kernel 3 (MFMA dense + target + final fused): 512 blocks = 64 row-groups
// (64 rows, 4 register-resident a-frag row-tiles) x 8 vocab eighths
// (~640 KB Wf each, L2-resident per XCD under round-robin %8). Per block:
// R14's sweep + inline target-logit capture (unique writer lane per row,
// llc_storef) + S partial via llc_storef. After the vmcnt-draining
// __syncthreads, tid0 bumps sdone[rg] (relaxed LLC RMW, NO waiting); the
// 8th arriver reads the 8 S partials + tl from the LLC and writes the 64
// perplexities. Proven drain->RMW->read ordering (R5/R10 barrier pattern).
// ---------------------------------------------------------------------------
__global__ __launch_bounds__(256, 1) void k_dense(
    const u16*   __restrict__ Hb,    // [BT][HIDN] bf16
    const u16*   __restrict__ Wf,    // [625][8][64][8]
    const float* __restrict__ bd,    // [VOCAB]
    const int*   __restrict__ tgt,   // [BT]
    float*                    S,     // [8][BT] partial sumexp
    float*                    tl,    // [BT] target logits
    u32*                      sdone, // [64] per-rg arrival counters (zeroed)
    float*       __restrict__ out)   // [BT] perplexity
{
    __shared__ float Sl[64];
    __shared__ int   tg[64];
    __shared__ u32   arrival;
    const int bid = blockIdx.x;
    const int hv  = bid & 7;                    // vocab eighth (XCD-aligned)
    const int rg  = bid >> 3;                   // 0..63
    const int r0  = rg * 64;
    const int tid = threadIdx.x;
    const int w   = tid >> 6, lane = tid & 63;
    const int m   = lane & 15, kq = lane >> 4;

    if (tid < 64) { Sl[tid] = 0.0f; tg[tid] = tgt[r0 + tid]; }

    v8s a[4][8];
    #pragma unroll
    for (int rt = 0; rt < 4; ++rt) {
        const u16* hrow = Hb + (size_t)(r0 + rt * 16 + m) * HIDN + kq * 8;
        #pragma unroll
        for (int q = 0; q < 8; ++q)
            a[rt][q] = *(const v8s*)(hrow + q * 32);
    }
    __syncthreads();

    float s[4][4] = {{0.f,0.f,0.f,0.f},{0.f,0.f,0.f,0.f},
                     {0.f,0.f,0.f,0.f},{0.f,0.f,0.f,0.f}};
    const int cbeg = (hv * NCT) >> 3;
    const int cend = ((hv + 1) * NCT) >> 3;
    for (int c = cbeg + w; c < cend; c += 4) {
        v4f acc[4] = {{0.f,0.f,0.f,0.f},{0.f,0.f,0.f,0.f},
                      {0.f,0.f,0.f,0.f},{0.f,0.f,0.f,0.f}};
        #pragma unroll
        for (int q = 0; q < 8; ++q) {
            v8s bq = *(const v8s*)(Wf + (((size_t)c * 8 + q) * 64 + lane) * 8);
            #pragma unroll
            for (int rt = 0; rt < 4; ++rt)
                acc[rt] = __builtin_amdgcn_mfma_f32_16x16x32_bf16(
                              a[rt][q], bq, acc[rt], 0, 0, 0);
        }
        const int col = c * 16 + m;
        const float bv = bd[col];
        #pragma unroll
        for (int rt = 0; rt < 4; ++rt)
            #pragma unroll
            for (int r = 0; r < 4; ++r) {
                float l = acc[rt][r] + bv;
                int row = rt * 16 + kq * 4 + r;       // batch row 0..63
                if (col == tg[row]) llc_storef(&tl[r0 + row], l);
                s[rt][r] += __expf(l);
            }
    }

    #pragma unroll
    for (int rt = 0; rt < 4; ++rt)
        #pragma unroll
        for (int r = 0; r < 4; ++r)
            atomicAdd(&Sl[rt * 16 + kq * 4 + r], s[rt][r]);
    __syncthreads();
    if (tid < 64) llc_storef(&S[(size_t)hv * BT + r0 + tid], Sl[tid]);
    __syncthreads();   // per-wave vmcnt(0): S + tl stores are at the LLC

    if (tid == 0) arrival = cnt_add(&sdone[rg]);
    __syncthreads();
    if (arrival == 7u) {           // 8th arriver: all 8 eighths published
        if (tid < 64) {
            float sum = 0.0f;
            #pragma unroll
            for (int p = 0; p < 8; ++p)
                sum += llc_loadf(&S[(size_t)p * BT + r0 + tid]);
            float tlv = llc_loadf(&tl[r0 + tid]);
            out[r0 + tid] = __expf(__logf(sum) - tlv);
        }
    }
}

// ---------------------------------------------------------------------------
extern "C" void kernel_launch(void* const* d_in, const int* in_sizes, int n_in,
                              void* d_out, int out_size, void* d_ws, size_t ws_size,
                              hipStream_t stream) {
    const int*   input   = (const int*)  d_in[0];   // [B,T]
    const int*   targets = (const int*)  d_in[1];   // [B,T]
    const float* E       = (const float*)d_in[2];   // [VOCAB,HID]
    const float* W_lstm  = (const float*)d_in[3];   // [2H,4H]
    const float* b_lstm  = (const float*)d_in[4];   // [4H]
    const float* W_dense = (const float*)d_in[5];   // [HID,VOCAB]
    const float* b_dense = (const float*)d_in[6];   // [VOCAB]
    float* out = (float*)d_out;                     // [B,T] perplexity

    char* ws = (char*)d_ws;
    const bool wide = (ws_size >= ((size_t)25 << 20));

    if (wide) {
        // 4-node layout: Wf in its own region; all weight transforms in one
        // prep node; dense+target+final fused. (~24.7 MB)
        //  [0,16M): gx | [16M,21.12M): Wf | [21.25M,23.25M): Hb
        //  [23.25M,+512K): Whf | [23.75M,+512K): Wxf | [24.25M,+64K): Hx
        //  [24.25M+64K,+128K): S | [24.25M+192K,+16K): tl
        //  [24.25M+208K,+1.25K): bar (plstm counters + sdone)
        float* gx  = (float*)ws;
        u16*   Wf  = (u16*)(ws + ((size_t)16 << 20));
        u16*   Hb  = (u16*)(ws + ((size_t)21 << 20) + ((size_t)256 << 10));
        u16*   Whf = (u16*)(ws + ((size_t)23 << 20) + ((size_t)256 << 10));
        u16*   Wxf = (u16*)(ws + ((size_t)23 << 20) + ((size_t)768 << 10));
        u16*   Hx  = (u16*)(ws + ((size_t)24 << 20) + ((size_t)256 << 10));
        float* S   = (float*)(ws + ((size_t)24 << 20) + ((size_t)320 << 10));
        float* tl  = (float*)(ws + ((size_t)24 << 20) + ((size_t)448 << 10));
        u32*   bar = (u32*)  (ws + ((size_t)24 << 20) + ((size_t)464 << 10));
        u32*   sdone = bar + 256;

        k_wfrag3<<<753,     256, 0, stream>>>(W_lstm, W_dense, Wxf, Whf, Wf, bar);
        k_xgates<<<BT / 16, 256, 0, stream>>>(input, E, Wxf, b_lstm, gx);
        k_plstm <<<64,      256, 0, stream>>>(Whf, gx, Hx, Hb, bar);
        k_dense <<<512,     256, 0, stream>>>(Hb, Wf, b_dense, targets,
                                              S, tl, sdone, out);
    } else {
        // 5-node fallback (Wf aliases gx after plstm).
        float* gx  = (float*)ws;
        u16*   Wf  = (u16*)ws;
        u16*   Hb  = (u16*)(ws + ((size_t)16 << 20));
        u16*   Whf = (u16*)(ws + ((size_t)18 << 20));
        u16*   Wxf = (u16*)(ws + ((size_t)18 << 20) + ((size_t)512 << 10));
        u16*   Hx  = (u16*)(ws + ((size_t)19 << 20));
        float* S   = (float*)(ws + ((size_t)19 << 20) + ((size_t)64 << 10));
        float* tl  = (float*)(ws + ((size_t)19 << 20) + ((size_t)192 << 10));
        u32*   bar = (u32*)  (ws + ((size_t)19 << 20) + ((size_t)208 << 10));
        u32*   sdone = bar + 256;

        k_wfrag2<<<128,     256, 0, stream>>>(W_lstm, Wxf, Whf, bar);
        k_xgates<<<BT / 16, 256, 0, stream>>>(input, E, Wxf, b_lstm, gx);
        k_plstm <<<64,      256, 0, stream>>>(Whf, gx, Hx, Hb, bar);
        k_wfrag <<<NCT,     256, 0, stream>>>(W_dense, Wf, VOCABN);
        k_dense <<<512,     256, 0, stream>>>(Hb, Wf, b_dense, targets,
                                              S, tl, sdone, out);
    }
}

// Round 17
// 354.493 us; speedup vs baseline: 1.0990x; 1.0990x over previous
//
#include <hip/hip_runtime.h>
#include <math.h>

// Problem constants (reference: VOCAB=10000, HID=256, B=64, T=64)
#define VOCABN 10000
#define HIDN   256
#define GATES  1024   // 4*HID
#define BN     64
#define TN     64
#define BT     4096   // B*T
#define NCT    625    // vocab col-tiles of 16 (10000 = 625*16 exactly)

typedef unsigned int       u32;
typedef unsigned short     u16;
typedef unsigned long long u64;
typedef float v4f __attribute__((ext_vector_type(4)));
typedef short v8s __attribute__((ext_vector_type(8)));

__device__ __forceinline__ float bf2f(u16 u) {
    return __uint_as_float(((u32)u) << 16);
}
__device__ __forceinline__ u16 f2bf(float f) {          // round-to-nearest-even
    u32 u = __float_as_uint(f);
    u += 0x7FFFu + ((u >> 16) & 1u);
    return (u16)(u >> 16);
}
__device__ __forceinline__ float fast_sigmoid(float x) {
    return 1.0f / (1.0f + __expf(-x));
}
__device__ __forceinline__ float fast_tanh(float x) {
    float e = __expf(-2.0f * fabsf(x));
    float t = (1.0f - e) / (1.0f + e);
    return copysignf(t, x);
}
__device__ __forceinline__ u64 llc_load(const u64* p) {
    return __hip_atomic_load(p, __ATOMIC_RELAXED, __HIP_MEMORY_SCOPE_AGENT);
}
__device__ __forceinline__ void llc_store(u64* p, u64 v) {
    __hip_atomic_store(p, v, __ATOMIC_RELAXED, __HIP_MEMORY_SCOPE_AGENT);
}
__device__ __forceinline__ u32 cnt_add(u32* p) {
    return __hip_atomic_fetch_add(p, 1u, __ATOMIC_RELAXED,
                                  __HIP_MEMORY_SCOPE_AGENT);
}
__device__ __forceinline__ u32 cnt_read(u32* p) {
    return __hip_atomic_load(p, __ATOMIC_RELAXED, __HIP_MEMORY_SCOPE_AGENT);
}

// ---------------------------------------------------------------------------
// fp32 [HIDN][ncols] tile c -> bf16 MFMA B-fragment layout [c][8 q][64 l][8].
// Fragment (c,q), lane l holds B[k = q*32 + (l>>4)*8 + j][n = c*16 + (l&15)].
// Plain uint4 stores (writer-L2 cached; cross-kernel visibility via the
// end-of-dispatch flush — consumers are always later launches).
// ---------------------------------------------------------------------------
__device__ __forceinline__ void wfrag_dev(
    const float* __restrict__ src, u16* __restrict__ dst, int ncols, int c,
    int t, u16 lt[HIDN][16])
{
    const float* s = src + (size_t)t * ncols + c * 16;
    #pragma unroll
    for (int j4 = 0; j4 < 4; ++j4) {
        float4 v = *(const float4*)(s + j4 * 4);
        lt[t][j4*4+0] = f2bf(v.x);
        lt[t][j4*4+1] = f2bf(v.y);
        lt[t][j4*4+2] = f2bf(v.z);
        lt[t][j4*4+3] = f2bf(v.w);
    }
    __syncthreads();
    #pragma unroll
    for (int h = 0; h < 2; ++h) {
        int f = t + h * 256;             // frag id = q*64 + l
        int q = f >> 6, l = f & 63;
        int m = l & 15, kb = q * 32 + ((l >> 4) & 3) * 8;
        u32 w[4];
        #pragma unroll
        for (int j = 0; j < 4; ++j)
            w[j] = (u32)lt[kb + 2*j][m] | ((u32)lt[kb + 2*j + 1][m] << 16);
        *(uint4*)(dst + (((size_t)c * 8 + q) * 64 + l) * 8) =
            make_uint4(w[0], w[1], w[2], w[3]);
    }
}

// ---------------------------------------------------------------------------
// wfrag for both W_lstm halves (128 blocks) — fallback-path prep. Block 0
// also zeroes the plstm barrier array.
// ---------------------------------------------------------------------------
__global__ __launch_bounds__(256) void k_wfrag2(
    const float* __restrict__ W_lstm,
    u16* __restrict__ Wxf, u16* __restrict__ Whf,
    u32* __restrict__ bar)           // [256] u32 (4 rg counters, 64-strided)
{
    __shared__ u16 lt[HIDN][16];
    const int bid = blockIdx.x;
    if (bid == 0) bar[threadIdx.x] = 0u;
    if (bid < 64)
        wfrag_dev(W_lstm, Wxf, GATES, bid, threadIdx.x, lt);
    else
        wfrag_dev(W_lstm + (size_t)HIDN * GATES, Whf, GATES, bid - 64,
                  threadIdx.x, lt);
}

// ---------------------------------------------------------------------------
// ALL THREE weight transforms in one launch (753 blocks) — wide-ws path.
//   0..63: W_lstm x-part -> Wxf | 64..127: h-part -> Whf | 128..752: W_dense
// Block 0 zeroes the plstm barrier array.
// ---------------------------------------------------------------------------
__global__ __launch_bounds__(256) void k_wfrag3(
    const float* __restrict__ W_lstm,
    const float* __restrict__ W_dense,
    u16* __restrict__ Wxf, u16* __restrict__ Whf, u16* __restrict__ Wf,
    u32* __restrict__ bar)
{
    __shared__ u16 lt[HIDN][16];
    const int bid = blockIdx.x;
    if (bid == 0) bar[threadIdx.x] = 0u;
    if (bid < 64)
        wfrag_dev(W_lstm, Wxf, GATES, bid, threadIdx.x, lt);
    else if (bid < 128)
        wfrag_dev(W_lstm + (size_t)HIDN * GATES, Whf, GATES, bid - 64,
                  threadIdx.x, lt);
    else
        wfrag_dev(W_dense, Wf, VOCABN, bid - 128, threadIdx.x, lt);
}

// ---------------------------------------------------------------------------
// wfrag for W_dense (625 blocks) — fallback path, runs AFTER plstm (Wf
// aliases gx there).
// ---------------------------------------------------------------------------
__global__ __launch_bounds__(256) void k_wfrag(
    const float* __restrict__ src,   // [HIDN][ncols]
    u16*         __restrict__ dst,   // [nct][8][64][8]
    int ncols)
{
    __shared__ u16 lt[HIDN][16];
    wfrag_dev(src, dst, ncols, blockIdx.x, threadIdx.x, lt);
}

// ---------------------------------------------------------------------------
// Kernel 1 (MFMA): gates_x = E[idx] @ W_x + b_lstm. 256 blocks x 16 rows.
// gx stays fp32: bf16 gx cost plstm +14us (R9 vs R10 A/B).
// ---------------------------------------------------------------------------
__global__ __launch_bounds__(256) void k_xgates(
    const int*   __restrict__ idx,   // [BT]
    const float* __restrict__ E,     // [VOCAB][HIDN]
    const u16*   __restrict__ Wxf,   // [64][8][64][8]
    const float* __restrict__ bl,    // [GATES]
    float*       __restrict__ gx)    // [BT][GATES]
{
    const int r0   = blockIdx.x * 16;
    const int tid  = threadIdx.x;
    const int w    = tid >> 6, lane = tid & 63;
    const int m    = lane & 15, quad = lane >> 4;

    v8s a[8];
    {
        const float* e = E + (size_t)idx[r0 + m] * HIDN + quad * 8;
        #pragma unroll
        for (int q = 0; q < 8; ++q) {
            float4 x0 = *(const float4*)(e + q * 32);
            float4 x1 = *(const float4*)(e + q * 32 + 4);
            uint4 t4 = make_uint4(
                (u32)f2bf(x0.x) | ((u32)f2bf(x0.y) << 16),
                (u32)f2bf(x0.z) | ((u32)f2bf(x0.w) << 16),
                (u32)f2bf(x1.x) | ((u32)f2bf(x1.y) << 16),
                (u32)f2bf(x1.z) | ((u32)f2bf(x1.w) << 16));
            a[q] = *(v8s*)&t4;
        }
    }

    for (int c = w; c < GATES / 16; c += 4) {
        v4f acc = {0.f, 0.f, 0.f, 0.f};
        #pragma unroll
        for (int q = 0; q < 8; ++q) {
            v8s b = *(const v8s*)(Wxf + (((size_t)c * 8 + q) * 64 + lane) * 8);
            acc = __builtin_amdgcn_mfma_f32_16x16x32_bf16(a[q], b, acc, 0, 0, 0);
        }
        const int col = c * 16 + m;
        const float bv = bl[col];
        #pragma unroll
        for (int r = 0; r < 4; ++r)   // D: col=lane&15, row=quad*4+r (m89/m91)
            gx[(size_t)(r0 + quad * 4 + r) * GATES + col] = acc[r] + bv;
    }
}

// ---------------------------------------------------------------------------
// Kernel 2 (persistent MFMA LSTM — R10/R14's proven 209us config VERBATIM):
// 64 blocks = 4 row-groups(16 rows) x 16 unit-slices. W_h slice LDS-resident.
// Cross-block h-exchange through the LLC ONLY via relaxed agent u64 ops.
// Counter barrier per step (flag-array variant was +11us, R12 A/B).
// Runs ALONE (R7/R8: co-running dense cost this kernel 1.7x).
// ---------------------------------------------------------------------------
__global__ __launch_bounds__(256) void k_plstm(
    const u16*   __restrict__ Whf,   // [64 ct][8][64][8] h-part frags
    const float* __restrict__ gx,    // [BT][GATES]
    u16*                      Hx,    // [2][BN][HIDN] bf16 exchange (LLC)
    u16*         __restrict__ Hb,    // [BT][HIDN] bf16 output
    u32*                      bar)   // counters (stride 64), zeroed by prep
{
    __shared__ uint4 Wl4[4 * 512];       // 32 KB: [ct][8 q][64 l][8] u16
    __shared__ float gl[4][16][16];      // 4 KB gate exchange

    const int tid  = threadIdx.x;
    const int rg   = blockIdx.x >> 4;    // row group: batch rows rg*16..+15
    const int ns   = blockIdx.x & 15;    // unit slice: units ns*16..+15
    const int u0   = ns * 16;
    const int w    = tid >> 6;           // wave = gate type (i,j,f,o)
    const int lane = tid & 63;
    const int m    = lane & 15, kq = lane >> 4;

    {   // load W_h slice: tiles c = w'*16 + ns, 8 KB contiguous each
        const uint4* src = (const uint4*)Whf;
        #pragma unroll
        for (int i = 0; i < 8; ++i) {
            int e  = tid + i * 256;          // [0, 2048)
            int ct = e >> 9, off = e & 511;  // 512 uint4 per tile
            Wl4[e] = src[(size_t)(ct * 16 + ns) * 512 + off];
        }
    }
    {   // zero gate-exchange so t=0 reads 0 for the h@W_h term
        float* g0 = (float*)gl;
        #pragma unroll
        for (int j = 0; j < 4; ++j) g0[tid * 4 + j] = 0.0f;
    }
    __syncthreads();

    const u16* Wl = (const u16*)Wl4;

    const int r = tid >> 4, u = tid & 15;
    const int b = rg * 16 + r;                       // batch row
    const float* gxp = gx + (size_t)b * TN * GATES + u0 + u;
    u16* hbp = Hb + (size_t)b * TN * HIDN + u0 + u;
    const int hxw = b * HIDN + u0 + u;               // Hx elem offset (in-buf)
    const int aoff = (rg * 16 + m) * HIDN + kq * 8;  // a-frag elem offset

    float cstate = 0.0f;
    float4 gxr;
    gxr.x = gxp[0]; gxr.y = gxp[256]; gxr.z = gxp[512]; gxr.w = gxp[768];

    for (int t = 0; t < TN; ++t) {
        // prefetch next step's x-gates early (hide HBM latency behind MFMA)
        float4 gxn = gxr;
        if (t + 1 < TN) {
            const float* p = gxp + (size_t)(t + 1) * GATES;
            gxn.x = p[0]; gxn.y = p[256]; gxn.z = p[512]; gxn.w = p[768];
        }

        if (t > 0) {
            // a-frags from LLC: relaxed agent u64 atomic loads (sc0 sc1)
            const u64* hsrc = (const u64*)(Hx + (t & 1) * (BN * HIDN) + aoff);
            v4f acc = {0.f, 0.f, 0.f, 0.f};
            #pragma unroll
            for (int q = 0; q < 8; ++q) {
                union { u64 d[2]; v8s v; } av;
                av.d[0] = llc_load(hsrc + q * 8);
                av.d[1] = llc_load(hsrc + q * 8 + 1);
                v8s bf = *(const v8s*)(Wl + ((w * 8 + q) * 64 + lane) * 8);
                acc = __builtin_amdgcn_mfma_f32_16x16x32_bf16(av.v, bf, acc, 0, 0, 0);
            }
            #pragma unroll
            for (int rr = 0; rr < 4; ++rr)   // row = kq*4+rr, col(unit) = m
                gl[w][kq * 4 + rr][m] = acc[rr];
        }
        __syncthreads();

        {   // cell update for (r, u); c stays in a register
            float ai = gl[0][r][u] + gxr.x;
            float aj = gl[1][r][u] + gxr.y;
            float af = gl[2][r][u] + gxr.z;
            float ao = gl[3][r][u] + gxr.w;
            float ig = fast_sigmoid(ai);
            float fg = fast_sigmoid(af + 1.0f);      // forget_bias = 1.0
            float og = fast_sigmoid(ao);
            float jt = fast_tanh(aj);
            cstate = fg * cstate + ig * jt;
            float hn = og * fast_tanh(cstate);
            u32 hv = f2bf(hn);
            hbp[(size_t)t * HIDN] = (u16)hv;

            if (t + 1 < TN) {
                // pack 4 consecutive units (same row, lanes tid..tid+3) into
                // one u64 and publish via relaxed agent atomic store -> LLC
                u32 p1 = __shfl_down(hv, 1);
                u32 p2 = __shfl_down(hv, 2);
                u32 p3 = __shfl_down(hv, 3);
                if ((tid & 3) == 0) {
                    u64 pk = (u64)(hv | (p1 << 16))
                           | ((u64)(p2 | (p3 << 16)) << 32);
                    u64* dst = (u64*)(Hx + (((t & 1) ^ 1) * (BN * HIDN)) + hxw);
                    llc_store(dst, pk);
                }
            }
        }

        if (t + 1 < TN) {
            __syncthreads();   // per-wave vmcnt(0) before s_barrier: all
                               // publish stores have reached the LLC
            if (tid == 0) {
                cnt_add(&bar[rg * 64]);
                u32 tgt = (u32)(t + 1) * 16u;
                while (cnt_read(&bar[rg * 64]) < tgt)
                    __builtin_amdgcn_s_sleep(1);
            }
            __syncthreads();   // broadcast release; also orders next gl writes
        }
        gxr = gxn;
    }
}

// ---------------------------------------------------------------------------
// Kernel 3 (MFMA dense, 8-way vocab split — R14 verbatim): 512 blocks =
// 64 row-groups(64 rows, 4 register-resident a-frag row-tiles) x 8 vocab
// eighths (~640 KB Wf each, L2-resident per XCD under round-robin %8).
// NOTE: R16's fused target/final epilogue regressed +33us (conditional
// LLC store in the hot loop) — keep the sweep pure.
// ---------------------------------------------------------------------------
__global__ __launch_bounds__(256, 1) void k_dense(
    const u16*   __restrict__ Hb,    // [BT][HIDN] bf16
    const u16*   __restrict__ Wf,    // [625][8][64][8]
    const float* __restrict__ bd,    // [VOCAB]
    float*       __restrict__ S)     // [8][BT] partial sumexp
{
    __shared__ float Sl[64];
    const int bid = blockIdx.x;
    const int hv  = bid & 7;                    // vocab eighth (XCD-aligned)
    const int rg  = bid >> 3;                   // 0..63
    const int r0  = rg * 64;
    const int tid = threadIdx.x;
    const int w   = tid >> 6, lane = tid & 63;
    const int m   = lane & 15, kq = lane >> 4;

    if (tid < 64) Sl[tid] = 0.0f;

    v8s a[4][8];
    #pragma unroll
    for (int rt = 0; rt < 4; ++rt) {
        const u16* hrow = Hb + (size_t)(r0 + rt * 16 + m) * HIDN + kq * 8;
        #pragma unroll
        for (int q = 0; q < 8; ++q)
            a[rt][q] = *(const v8s*)(hrow + q * 32);
    }
    __syncthreads();

    float s[4][4] = {{0.f,0.f,0.f,0.f},{0.f,0.f,0.f,0.f},
                     {0.f,0.f,0.f,0.f},{0.f,0.f,0.f,0.f}};
    const int cbeg = (hv * NCT) >> 3;
    const int cend = ((hv + 1) * NCT) >> 3;
    for (int c = cbeg + w; c < cend; c += 4) {
        v4f acc[4] = {{0.f,0.f,0.f,0.f},{0.f,0.f,0.f,0.f},
                      {0.f,0.f,0.f,0.f},{0.f,0.f,0.f,0.f}};
        #pragma unroll
        for (int q = 0; q < 8; ++q) {
            v8s bq = *(const v8s*)(Wf + (((size_t)c * 8 + q) * 64 + lane) * 8);
            #pragma unroll
            for (int rt = 0; rt < 4; ++rt)
                acc[rt] = __builtin_amdgcn_mfma_f32_16x16x32_bf16(
                              a[rt][q], bq, acc[rt], 0, 0, 0);
        }
        const float bv = bd[c * 16 + m];
        #pragma unroll
        for (int rt = 0; rt < 4; ++rt)
            #pragma unroll
            for (int r = 0; r < 4; ++r)
                s[rt][r] += __expf(acc[rt][r] + bv);
    }

    #pragma unroll
    for (int rt = 0; rt < 4; ++rt)
        #pragma unroll
        for (int r = 0; r < 4; ++r)
            atomicAdd(&Sl[rt * 16 + kq * 4 + r], s[rt][r]);
    __syncthreads();
    if (tid < 64) S[(size_t)hv * BT + r0 + tid] = Sl[tid];
}

// ---------------------------------------------------------------------------
// Kernel 4 (target + final fused — R14 verbatim): per row, dot h with the
// target's W column (32 thr/row), then ppl = exp(log(sum S) - logit).
// ---------------------------------------------------------------------------
__global__ __launch_bounds__(256) void k_target(
    const u16*   __restrict__ Hb,
    const u16*   __restrict__ Wf,
    const float* __restrict__ bd,
    const int*   __restrict__ tgt,
    const float* __restrict__ S,     // [8][BT]
    float*       __restrict__ out)   // [BT]
{
    const int tid = threadIdx.x;
    const int row = blockIdx.x * 8 + (tid >> 5);
    const int t   = tid & 31;
    const int q   = t >> 2, lq = t & 3;
    const int v   = tgt[row];
    const int c   = v >> 4, vm = v & 15;
    const int kb  = q * 32 + lq * 8;

    v8s h  = *(const v8s*)(Hb + (size_t)row * HIDN + kb);
    v8s wv = *(const v8s*)(Wf + (((size_t)c * 8 + q) * 64 + lq * 16 + vm) * 8);
    float acc = 0.0f;
    #pragma unroll
    for (int j = 0; j < 8; ++j)
        acc = fmaf(bf2f((u16)h[j]), bf2f((u16)wv[j]), acc);
    #pragma unroll
    for (int off = 16; off >= 1; off >>= 1)
        acc += __shfl_down(acc, off, 32);
    if (t == 0) {
        float tlv = acc + bd[v];
        float sum = 0.0f;
        #pragma unroll
        for (int p = 0; p < 8; ++p) sum += S[(size_t)p * BT + row];
        out[row] = __expf(__logf(sum) - tlv);
    }
}

// ---------------------------------------------------------------------------
extern "C" void kernel_launch(void* const* d_in, const int* in_sizes, int n_in,
                              void* d_out, int out_size, void* d_ws, size_t ws_size,
                              hipStream_t stream) {
    const int*   input   = (const int*)  d_in[0];   // [B,T]
    const int*   targets = (const int*)  d_in[1];   // [B,T]
    const float* E       = (const float*)d_in[2];   // [VOCAB,HID]
    const float* W_lstm  = (const float*)d_in[3];   // [2H,4H]
    const float* b_lstm  = (const float*)d_in[4];   // [4H]
    const float* W_dense = (const float*)d_in[5];   // [HID,VOCAB]
    const float* b_dense = (const float*)d_in[6];   // [VOCAB]
    float* out = (float*)d_out;                     // [B,T] perplexity

    char* ws = (char*)d_ws;
    const bool wide = (ws_size >= ((size_t)25 << 20));

    if (wide) {
        // 5-node layout: Wf gets its own region; ALL weight transforms in
        // one prep node before xgates. (~24.5 MB)
        //  [0,16M): gx | [16M,21.12M): Wf | [21.25M,23.25M): Hb
        //  [23.25M,+512K): Whf | [23.75M,+512K): Wxf | [24.25M,+64K): Hx
        //  [24.25M+64K,+128K): S | [24.25M+192K,+1K): bar
        float* gx  = (float*)ws;
        u16*   Wf  = (u16*)(ws + ((size_t)16 << 20));
        u16*   Hb  = (u16*)(ws + ((size_t)21 << 20) + ((size_t)256 << 10));
        u16*   Whf = (u16*)(ws + ((size_t)23 << 20) + ((size_t)256 << 10));
        u16*   Wxf = (u16*)(ws + ((size_t)23 << 20) + ((size_t)768 << 10));
        u16*   Hx  = (u16*)(ws + ((size_t)24 << 20) + ((size_t)256 << 10));
        float* S   = (float*)(ws + ((size_t)24 << 20) + ((size_t)320 << 10));
        u32*   bar = (u32*)  (ws + ((size_t)24 << 20) + ((size_t)448 << 10));

        k_wfrag3<<<753,     256, 0, stream>>>(W_lstm, W_dense, Wxf, Whf, Wf, bar);
        k_xgates<<<BT / 16, 256, 0, stream>>>(input, E, Wxf, b_lstm, gx);
        k_plstm <<<64,      256, 0, stream>>>(Whf, gx, Hx, Hb, bar);
        k_dense <<<512,     256, 0, stream>>>(Hb, Wf, b_dense, S);
        k_target<<<BT / 8,  256, 0, stream>>>(Hb, Wf, b_dense, targets, S, out);
    } else {
        // 6-node fallback — R14 layout verbatim (Wf aliases gx after plstm).
        float* gx  = (float*)ws;
        u16*   Wf  = (u16*)ws;
        u16*   Hb  = (u16*)(ws + ((size_t)16 << 20));
        u16*   Whf = (u16*)(ws + ((size_t)18 << 20));
        u16*   Wxf = (u16*)(ws + ((size_t)18 << 20) + ((size_t)512 << 10));
        u16*   Hx  = (u16*)(ws + ((size_t)19 << 20));
        float* S   = (float*)(ws + ((size_t)19 << 20) + ((size_t)64 << 10));
        u32*   bar = (u32*)  (ws + ((size_t)19 << 20) + ((size_t)192 << 10));

        k_wfrag2<<<128,     256, 0, stream>>>(W_lstm, Wxf, Whf, bar);
        k_xgates<<<BT / 16, 256, 0, stream>>>(input, E, Wxf, b_lstm, gx);
        k_plstm <<<64,      256, 0, stream>>>(Whf, gx, Hx, Hb, bar);
        k_wfrag <<<NCT,     256, 0, stream>>>(W_dense, Wf, VOCABN);
        k_dense <<<512,     256, 0, stream>>>(Hb, Wf, b_dense, S);
        k_target<<<BT / 8,  256, 0, stream>>>(Hb, Wf, b_dense, targets, S, out);
    }
}